// Round 2
// baseline (2931.658 us; speedup 1.0000x reference)
//
#include <hip/hip_runtime.h>
#include <stdint.h>

// GATConv: N=100000 nodes, E=1600000 edges, IN=128, HEADS=4, OUT=32 (HO=128)
// All float tensors are fp32 (reference dtype); edge_index delivered as int32.
// Pipeline: memset(num,den) -> gemm(h=x@W fp32) -> s-kernel (s_src,s_tgt)
//           -> edge scatter (fp32 atomics into num/den) -> finalize.

#define NN 100000
#define EE 1600000
#define INCH 128
#define HO 128           // HEADS*OUT
#define HEADS 4
#define OUTC 32

// ---------------- GEMM: h[n][c] = sum_k x[n][k] * W[k][c]
// W fully LDS-resident (64KB); 32-row x tile (16KB); 256 thr, 4x4 per thread.
__global__ __launch_bounds__(256) void gemm_h(const float* __restrict__ x,
                                              const float* __restrict__ W,
                                              float* __restrict__ h) {
    __shared__ __align__(16) float wsm[128 * 128];   // 64 KB
    __shared__ __align__(16) float xs[32 * 128];     // 16 KB
    const int tid = threadIdx.x;

    const float4* W4 = (const float4*)W;
    float4* w4 = (float4*)wsm;
#pragma unroll
    for (int i = 0; i < 16; ++i) w4[tid + 256 * i] = W4[tid + 256 * i];

    const float4* x4 = (const float4*)(x + (size_t)blockIdx.x * 32 * INCH);
    float4* xs4 = (float4*)xs;
#pragma unroll
    for (int i = 0; i < 4; ++i) xs4[tid + 256 * i] = x4[tid + 256 * i];
    __syncthreads();

    const int rg = tid >> 5, cg = tid & 31;
    const int r0 = rg * 4, c0 = cg * 4;
    float acc[4][4] = {};
#pragma unroll 8
    for (int k = 0; k < 128; ++k) {
        const float4 wv = *(const float4*)(wsm + k * 128 + c0);
        float xv[4];
#pragma unroll
        for (int i = 0; i < 4; ++i) xv[i] = xs[(r0 + i) * 128 + k];
#pragma unroll
        for (int i = 0; i < 4; ++i) {
            acc[i][0] = fmaf(xv[i], wv.x, acc[i][0]);
            acc[i][1] = fmaf(xv[i], wv.y, acc[i][1]);
            acc[i][2] = fmaf(xv[i], wv.z, acc[i][2]);
            acc[i][3] = fmaf(xv[i], wv.w, acc[i][3]);
        }
    }
#pragma unroll
    for (int i = 0; i < 4; ++i) {
        float4 st = {acc[i][0], acc[i][1], acc[i][2], acc[i][3]};
        *(float4*)(h + (size_t)(blockIdx.x * 32 + r0 + i) * HO + c0) = st;
    }
}

// ---------------- s_src/s_tgt: per (node, head) dot of h with attention halves
// 8 lanes per (n,hd) pair; 32 pairs per 256-thread block.
__global__ __launch_bounds__(256) void s_kernel(const float* __restrict__ h,
                                                const float* __restrict__ att,
                                                float* __restrict__ s_src,
                                                float* __restrict__ s_tgt) {
    __shared__ float a[256];
    const int tid = threadIdx.x;
    a[tid] = att[tid];               // attention[4][64] = 256 floats
    __syncthreads();
    const int g = (blockIdx.x * 256 + tid) >> 3;   // pair index, exact grid
    const int l = tid & 7;
    const int n = g >> 2, hd = g & 3;
    const float4 v = *(const float4*)(h + (size_t)n * HO + hd * OUTC + l * 4);
    const int ao = hd * 64 + l * 4;
    float ss = v.x * a[ao] + v.y * a[ao + 1] + v.z * a[ao + 2] + v.w * a[ao + 3];
    float st = v.x * a[ao + 32] + v.y * a[ao + 33] + v.z * a[ao + 34] + v.w * a[ao + 35];
#pragma unroll
    for (int d = 1; d < 8; d <<= 1) {
        ss += __shfl_xor(ss, d, 64);
        st += __shfl_xor(st, d, 64);
    }
    if (l == 0) { s_src[g] = ss; s_tgt[g] = st; }
}

// ---------------- edge scatter: 32 lanes per edge, 4 channels per lane
__global__ __launch_bounds__(256) void scatter_k(const int* __restrict__ ei,
                                                 const float* __restrict__ h,
                                                 const float* __restrict__ s_src,
                                                 const float* __restrict__ s_tgt,
                                                 float* __restrict__ num,
                                                 float* __restrict__ den) {
    const long long gid = (long long)blockIdx.x * 256 + threadIdx.x;
    const int e = (int)(gid >> 5);
    if (e >= EE) return;
    const int l = (int)(gid & 31);
    const int src = ei[e];
    const int tgt = ei[EE + e];
    const int hd = l >> 3;
    float score = s_src[src * 4 + hd] + s_tgt[tgt * 4 + hd];
    float lr = score > 0.f ? score : 0.2f * score;
    float w = __expf(-lr);
    const int c0 = l * 4;
    const float4 v = *(const float4*)(h + (size_t)src * HO + c0);
    float* np_ = num + (size_t)tgt * HO + c0;
    unsafeAtomicAdd(np_ + 0, w * v.x);
    unsafeAtomicAdd(np_ + 1, w * v.y);
    unsafeAtomicAdd(np_ + 2, w * v.z);
    unsafeAtomicAdd(np_ + 3, w * v.w);
    if ((l & 7) == 0) unsafeAtomicAdd(den + tgt * 4 + hd, w);
}

// ---------------- finalize: out = num / clip(den, eps) + bias
__global__ __launch_bounds__(256) void finalize_k(const float* __restrict__ num,
                                                  const float* __restrict__ den,
                                                  const float* __restrict__ bias,
                                                  float* __restrict__ out) {
    const int t = blockIdx.x * 256 + threadIdx.x;   // one thread per 4 channels
    const int n = t >> 5;
    const int q = t & 31;
    const int c0 = q * 4;
    const int hd = q >> 3;
    float d = den[n * 4 + hd];
    d = fmaxf(d, 1e-10f);
    float inv = 1.0f / d;
    float4 nv = *(const float4*)(num + (size_t)n * HO + c0);
    float4 st;
    st.x = nv.x * inv + bias[c0];
    st.y = nv.y * inv + bias[c0 + 1];
    st.z = nv.z * inv + bias[c0 + 2];
    st.w = nv.w * inv + bias[c0 + 3];
    *(float4*)(out + (size_t)n * HO + c0) = st;
}

extern "C" void kernel_launch(void* const* d_in, const int* in_sizes, int n_in,
                              void* d_out, int out_size, void* d_ws, size_t ws_size,
                              hipStream_t stream) {
    const float* x    = (const float*)d_in[0];
    const int*   ei   = (const int*)d_in[1];
    const float* W    = (const float*)d_in[2];
    const float* att  = (const float*)d_in[3];
    const float* bias = (const float*)d_in[4];
    float* out = (float*)d_out;

    char* ws = (char*)d_ws;
    const size_t NUM_B = (size_t)NN * HO * 4;        // 51.2 MB
    const size_t DEN_B = (size_t)NN * HEADS * 4;     // 1.6 MB
    const size_t H_B   = (size_t)NN * HO * 4;        // 51.2 MB
    const size_t S_B   = (size_t)NN * HEADS * 4;     // 1.6 MB
    float* num  = (float*)ws;
    float* den  = (float*)(ws + NUM_B);
    float* h    = (float*)(ws + NUM_B + DEN_B);
    float* ssrc = (float*)(ws + NUM_B + DEN_B + H_B);
    float* stgt = (float*)(ws + NUM_B + DEN_B + H_B + S_B);

    hipMemsetAsync(num, 0, NUM_B + DEN_B, stream);   // zero num+den (adjacent)

    gemm_h<<<NN / 32, 256, 0, stream>>>(x, W, h);                        // 3125 blocks
    s_kernel<<<(NN * HEADS) / 32, 256, 0, stream>>>(h, att, ssrc, stgt); // 12500 blocks
    scatter_k<<<(EE * 32) / 256, 256, 0, stream>>>(ei, h, ssrc, stgt, num, den); // 200000 blocks
    finalize_k<<<(NN * 32) / 256, 256, 0, stream>>>(num, den, bias, out); // 12500 blocks
}

// Round 3
// 709.367 us; speedup vs baseline: 4.1328x; 4.1328x over previous
//
#include <hip/hip_runtime.h>
#include <stdint.h>

// GATConv: N=100000 nodes, E=1600000 edges, IN=128, HEADS=4, OUT=32 (HO=128)
// fp32 tensors; edge_index int32.
//
// R3 structure (atomic-free aggregation):
//   gemm(h=x@W) -> s_kernel -> hist(deg) -> scan(offs,cursor)
//   -> fillsort (counting-sort edges by tgt, precompute per-edge head weights)
//   -> gather (one wave per node: pull, reduce in regs, finalize fused)

#define NN 100000
#define EE 1600000
#define INCH 128
#define HO 128           // HEADS*OUT
#define HEADS 4
#define OUTC 32

// ---------------- GEMM: h[n][c] = sum_k x[n][k] * W[k][c]
__global__ __launch_bounds__(256) void gemm_h(const float* __restrict__ x,
                                              const float* __restrict__ W,
                                              float* __restrict__ h) {
    __shared__ __align__(16) float wsm[128 * 128];   // 64 KB
    __shared__ __align__(16) float xs[32 * 128];     // 16 KB
    const int tid = threadIdx.x;

    const float4* W4 = (const float4*)W;
    float4* w4 = (float4*)wsm;
#pragma unroll
    for (int i = 0; i < 16; ++i) w4[tid + 256 * i] = W4[tid + 256 * i];

    const float4* x4 = (const float4*)(x + (size_t)blockIdx.x * 32 * INCH);
    float4* xs4 = (float4*)xs;
#pragma unroll
    for (int i = 0; i < 4; ++i) xs4[tid + 256 * i] = x4[tid + 256 * i];
    __syncthreads();

    const int rg = tid >> 5, cg = tid & 31;
    const int r0 = rg * 4, c0 = cg * 4;
    float acc[4][4] = {};
#pragma unroll 8
    for (int k = 0; k < 128; ++k) {
        const float4 wv = *(const float4*)(wsm + k * 128 + c0);
        float xv[4];
#pragma unroll
        for (int i = 0; i < 4; ++i) xv[i] = xs[(r0 + i) * 128 + k];
#pragma unroll
        for (int i = 0; i < 4; ++i) {
            acc[i][0] = fmaf(xv[i], wv.x, acc[i][0]);
            acc[i][1] = fmaf(xv[i], wv.y, acc[i][1]);
            acc[i][2] = fmaf(xv[i], wv.z, acc[i][2]);
            acc[i][3] = fmaf(xv[i], wv.w, acc[i][3]);
        }
    }
#pragma unroll
    for (int i = 0; i < 4; ++i) {
        float4 st = {acc[i][0], acc[i][1], acc[i][2], acc[i][3]};
        *(float4*)(h + (size_t)(blockIdx.x * 32 + r0 + i) * HO + c0) = st;
    }
}

// ---------------- s_src/s_tgt: per (node, head) dots with attention halves
__global__ __launch_bounds__(256) void s_kernel(const float* __restrict__ h,
                                                const float* __restrict__ att,
                                                float* __restrict__ s_src,
                                                float* __restrict__ s_tgt) {
    __shared__ float a[256];
    const int tid = threadIdx.x;
    a[tid] = att[tid];               // attention[4][64] = 256 floats
    __syncthreads();
    const int g = (blockIdx.x * 256 + tid) >> 3;   // (n,head) pair index
    const int l = tid & 7;
    const int n = g >> 2, hd = g & 3;
    const float4 v = *(const float4*)(h + (size_t)n * HO + hd * OUTC + l * 4);
    const int ao = hd * 64 + l * 4;
    float ss = v.x * a[ao] + v.y * a[ao + 1] + v.z * a[ao + 2] + v.w * a[ao + 3];
    float st = v.x * a[ao + 32] + v.y * a[ao + 33] + v.z * a[ao + 34] + v.w * a[ao + 35];
#pragma unroll
    for (int d = 1; d < 8; d <<= 1) {
        ss += __shfl_xor(ss, d, 64);
        st += __shfl_xor(st, d, 64);
    }
    if (l == 0) { s_src[g] = ss; s_tgt[g] = st; }
}

// ---------------- histogram of tgt degrees
__global__ __launch_bounds__(256) void hist_k(const int* __restrict__ ei,
                                              int* __restrict__ deg) {
    const int e = blockIdx.x * 256 + threadIdx.x;
    if (e < EE) atomicAdd(deg + ei[EE + e], 1);
}

// ---------------- single-block exclusive scan: deg -> offs, cursor
__global__ __launch_bounds__(1024) void scan_k(const int* __restrict__ deg,
                                               int* __restrict__ offs,
                                               int* __restrict__ cursor) {
    __shared__ int part[1024];
    const int t = threadIdx.x;
    const int CH = 98;                 // 1024*98 = 100352 >= NN
    const int base = t * CH;
    int s = 0;
    for (int i = 0; i < CH; ++i) {
        int idx = base + i;
        if (idx < NN) s += deg[idx];
    }
    part[t] = s;
    __syncthreads();
    // inclusive Hillis-Steele
    for (int off = 1; off < 1024; off <<= 1) {
        int v = (t >= off) ? part[t - off] : 0;
        __syncthreads();
        part[t] += v;
        __syncthreads();
    }
    int run = (t == 0) ? 0 : part[t - 1];
    for (int i = 0; i < CH; ++i) {
        int idx = base + i;
        if (idx < NN) {
            int d = deg[idx];
            offs[idx] = run;
            cursor[idx] = run;
            run += d;
        }
    }
    if (t == 0) offs[NN] = EE;
}

// ---------------- counting-sort fill + per-edge head weights
__global__ __launch_bounds__(256) void fillsort_k(const int* __restrict__ ei,
                                                  const float* __restrict__ s_src,
                                                  const float* __restrict__ s_tgt,
                                                  int* __restrict__ cursor,
                                                  int* __restrict__ sorted_src,
                                                  float4* __restrict__ wts) {
    const int e = blockIdx.x * 256 + threadIdx.x;
    if (e >= EE) return;
    const int src = ei[e];
    const int tgt = ei[EE + e];
    const float4 a = *(const float4*)(s_src + (size_t)src * 4);
    const float4 b = *(const float4*)(s_tgt + (size_t)tgt * 4);
    float sc[4] = {a.x + b.x, a.y + b.y, a.z + b.z, a.w + b.w};
    float w[4];
#pragma unroll
    for (int i = 0; i < 4; ++i) {
        float lr = sc[i] > 0.f ? sc[i] : 0.2f * sc[i];
        w[i] = __expf(-lr);
    }
    const int pos = atomicAdd(cursor + tgt, 1);
    sorted_src[pos] = src;
    wts[pos] = make_float4(w[0], w[1], w[2], w[3]);
}

// ---------------- gather: one wave per node, finalize fused
__global__ __launch_bounds__(256) void gather_k(const int* __restrict__ offs,
                                                const int* __restrict__ sorted_src,
                                                const float* __restrict__ wts,
                                                const float* __restrict__ h,
                                                const float* __restrict__ bias,
                                                float* __restrict__ out) {
    const int n = blockIdx.x * 4 + (threadIdx.x >> 6);
    const int l = threadIdx.x & 63;
    const int c0 = l * 2;              // each lane: channels c0, c0+1 (same head)
    const int hd = l >> 4;
    const int p0 = offs[n], p1 = offs[n + 1];
    float ax = 0.f, ay = 0.f, wsum = 0.f;
    int p = p0;
    for (; p + 1 < p1; p += 2) {
        const int s0 = sorted_src[p];
        const int s1 = sorted_src[p + 1];
        const float w0 = wts[(size_t)p * 4 + hd];
        const float w1 = wts[(size_t)(p + 1) * 4 + hd];
        const float2 h0 = *(const float2*)(h + (size_t)s0 * HO + c0);
        const float2 h1 = *(const float2*)(h + (size_t)s1 * HO + c0);
        ax = fmaf(w0, h0.x, ax); ay = fmaf(w0, h0.y, ay);
        ax = fmaf(w1, h1.x, ax); ay = fmaf(w1, h1.y, ay);
        wsum += w0 + w1;
    }
    if (p < p1) {
        const int s0 = sorted_src[p];
        const float w0 = wts[(size_t)p * 4 + hd];
        const float2 h0 = *(const float2*)(h + (size_t)s0 * HO + c0);
        ax = fmaf(w0, h0.x, ax); ay = fmaf(w0, h0.y, ay);
        wsum += w0;
    }
    const float inv = 1.f / fmaxf(wsum, 1e-10f);
    float2 o;
    o.x = ax * inv + bias[c0];
    o.y = ay * inv + bias[c0 + 1];
    *(float2*)(out + (size_t)n * HO + c0) = o;
}

extern "C" void kernel_launch(void* const* d_in, const int* in_sizes, int n_in,
                              void* d_out, int out_size, void* d_ws, size_t ws_size,
                              hipStream_t stream) {
    const float* x    = (const float*)d_in[0];
    const int*   ei   = (const int*)d_in[1];
    const float* W    = (const float*)d_in[2];
    const float* att  = (const float*)d_in[3];
    const float* bias = (const float*)d_in[4];
    float* out = (float*)d_out;

    char* ws = (char*)d_ws;
    const size_t H_B   = (size_t)NN * HO * 4;        // 51.2 MB
    const size_t WT_B  = (size_t)EE * 16;            // 25.6 MB
    const size_t SS_B  = (size_t)EE * 4;             // 6.4 MB
    const size_t S_B   = (size_t)NN * HEADS * 4;     // 1.6 MB
    const size_t DEG_B = (size_t)NN * 4;             // 400 KB
    const size_t OFF_B = ((size_t)(NN + 1) * 4 + 15) & ~15ull;

    size_t o = 0;
    float*  h          = (float*)(ws + o); o += H_B;
    float4* wts        = (float4*)(ws + o); o += WT_B;
    int*    sorted_src = (int*)(ws + o); o += SS_B;
    float*  ssrc       = (float*)(ws + o); o += S_B;
    float*  stgt       = (float*)(ws + o); o += S_B;
    int*    deg        = (int*)(ws + o); o += DEG_B;
    int*    offs       = (int*)(ws + o); o += OFF_B;
    int*    cursor     = (int*)(ws + o); o += DEG_B;

    hipMemsetAsync(deg, 0, DEG_B, stream);

    gemm_h<<<NN / 32, 256, 0, stream>>>(x, W, h);                         // 3125 blocks
    s_kernel<<<(NN * HEADS) / 32, 256, 0, stream>>>(h, att, ssrc, stgt);  // 12500 blocks
    hist_k<<<(EE + 255) / 256, 256, 0, stream>>>(ei, deg);                // 6250 blocks
    scan_k<<<1, 1024, 0, stream>>>(deg, offs, cursor);
    fillsort_k<<<(EE + 255) / 256, 256, 0, stream>>>(ei, ssrc, stgt, cursor,
                                                     sorted_src, wts);    // 6250 blocks
    gather_k<<<NN / 4, 256, 0, stream>>>(offs, sorted_src, (const float*)wts,
                                         h, bias, out);                   // 25000 blocks
}

// Round 4
// 447.758 us; speedup vs baseline: 6.5474x; 1.5843x over previous
//
#include <hip/hip_runtime.h>
#include <stdint.h>

// GATConv: N=100000 nodes, E=1600000 edges, IN=128, HEADS=4, OUT=32 (HO=128)
// fp32 tensors; edge_index int32.
//
// R4: R3 structure but the single-block scan (265us, 37% of total) replaced
// with a 3-kernel parallel scan (blocksum -> scan of 250 sums -> apply).

#define NN 100000
#define EE 1600000
#define INCH 128
#define HO 128           // HEADS*OUT
#define HEADS 4
#define OUTC 32

#define SCAN_BLOCKS 250  // 250 * 400 = 100000
#define CHUNK 400        // elements per scan block (200 int2)

// ---------------- GEMM: h[n][c] = sum_k x[n][k] * W[k][c]
__global__ __launch_bounds__(256) void gemm_h(const float* __restrict__ x,
                                              const float* __restrict__ W,
                                              float* __restrict__ h) {
    __shared__ __align__(16) float wsm[128 * 128];   // 64 KB
    __shared__ __align__(16) float xs[32 * 128];     // 16 KB
    const int tid = threadIdx.x;

    const float4* W4 = (const float4*)W;
    float4* w4 = (float4*)wsm;
#pragma unroll
    for (int i = 0; i < 16; ++i) w4[tid + 256 * i] = W4[tid + 256 * i];

    const float4* x4 = (const float4*)(x + (size_t)blockIdx.x * 32 * INCH);
    float4* xs4 = (float4*)xs;
#pragma unroll
    for (int i = 0; i < 4; ++i) xs4[tid + 256 * i] = x4[tid + 256 * i];
    __syncthreads();

    const int rg = tid >> 5, cg = tid & 31;
    const int r0 = rg * 4, c0 = cg * 4;
    float acc[4][4] = {};
#pragma unroll 8
    for (int k = 0; k < 128; ++k) {
        const float4 wv = *(const float4*)(wsm + k * 128 + c0);
        float xv[4];
#pragma unroll
        for (int i = 0; i < 4; ++i) xv[i] = xs[(r0 + i) * 128 + k];
#pragma unroll
        for (int i = 0; i < 4; ++i) {
            acc[i][0] = fmaf(xv[i], wv.x, acc[i][0]);
            acc[i][1] = fmaf(xv[i], wv.y, acc[i][1]);
            acc[i][2] = fmaf(xv[i], wv.z, acc[i][2]);
            acc[i][3] = fmaf(xv[i], wv.w, acc[i][3]);
        }
    }
#pragma unroll
    for (int i = 0; i < 4; ++i) {
        float4 st = {acc[i][0], acc[i][1], acc[i][2], acc[i][3]};
        *(float4*)(h + (size_t)(blockIdx.x * 32 + r0 + i) * HO + c0) = st;
    }
}

// ---------------- s_src/s_tgt: per (node, head) dots with attention halves
__global__ __launch_bounds__(256) void s_kernel(const float* __restrict__ h,
                                                const float* __restrict__ att,
                                                float* __restrict__ s_src,
                                                float* __restrict__ s_tgt) {
    __shared__ float a[256];
    const int tid = threadIdx.x;
    a[tid] = att[tid];               // attention[4][64] = 256 floats
    __syncthreads();
    const int g = (blockIdx.x * 256 + tid) >> 3;   // (n,head) pair index
    const int l = tid & 7;
    const int n = g >> 2, hd = g & 3;
    const float4 v = *(const float4*)(h + (size_t)n * HO + hd * OUTC + l * 4);
    const int ao = hd * 64 + l * 4;
    float ss = v.x * a[ao] + v.y * a[ao + 1] + v.z * a[ao + 2] + v.w * a[ao + 3];
    float st = v.x * a[ao + 32] + v.y * a[ao + 33] + v.z * a[ao + 34] + v.w * a[ao + 35];
#pragma unroll
    for (int d = 1; d < 8; d <<= 1) {
        ss += __shfl_xor(ss, d, 64);
        st += __shfl_xor(st, d, 64);
    }
    if (l == 0) { s_src[g] = ss; s_tgt[g] = st; }
}

// ---------------- histogram of tgt degrees
__global__ __launch_bounds__(256) void hist_k(const int* __restrict__ ei,
                                              int* __restrict__ deg) {
    const int e = blockIdx.x * 256 + threadIdx.x;
    if (e < EE) atomicAdd(deg + ei[EE + e], 1);
}

// ---------------- scan pass 1: per-block chunk sums
__global__ __launch_bounds__(256) void blocksum_k(const int* __restrict__ deg,
                                                  int* __restrict__ blockSums) {
    __shared__ int red[256];
    const int t = threadIdx.x;
    const int i2 = blockIdx.x * 200 + t;     // int2 index, 200 per block
    int s = 0;
    if (t < 200) {
        const int2 d = ((const int2*)deg)[i2];
        s = d.x + d.y;
    }
    red[t] = s;
    __syncthreads();
#pragma unroll
    for (int off = 128; off > 0; off >>= 1) {
        if (t < off) red[t] += red[t + off];
        __syncthreads();
    }
    if (t == 0) blockSums[blockIdx.x] = red[0];
}

// ---------------- scan pass 2: exclusive scan of 250 block sums
__global__ __launch_bounds__(256) void scansums_k(const int* __restrict__ blockSums,
                                                  int* __restrict__ blockOffs,
                                                  int* __restrict__ offs) {
    __shared__ int p[256];
    const int t = threadIdx.x;
    int v = (t < SCAN_BLOCKS) ? blockSums[t] : 0;
    p[t] = v;
    __syncthreads();
#pragma unroll
    for (int off = 1; off < 256; off <<= 1) {
        int u = (t >= off) ? p[t - off] : 0;
        __syncthreads();
        p[t] += u;
        __syncthreads();
    }
    if (t < SCAN_BLOCKS) blockOffs[t] = p[t] - v;   // exclusive
    if (t == 0) offs[NN] = EE;
}

// ---------------- scan pass 3: apply — write offs & cursor
__global__ __launch_bounds__(256) void scanapply_k(const int* __restrict__ deg,
                                                   const int* __restrict__ blockOffs,
                                                   int* __restrict__ offs,
                                                   int* __restrict__ cursor) {
    __shared__ int p[256];
    const int t = threadIdx.x;
    const int i2 = blockIdx.x * 200 + t;
    int2 d = make_int2(0, 0);
    if (t < 200) d = ((const int2*)deg)[i2];
    const int s = d.x + d.y;
    p[t] = s;
    __syncthreads();
#pragma unroll
    for (int off = 1; off < 256; off <<= 1) {
        int u = (t >= off) ? p[t - off] : 0;
        __syncthreads();
        p[t] += u;
        __syncthreads();
    }
    if (t < 200) {
        const int run = blockOffs[blockIdx.x] + p[t] - s;   // exclusive prefix
        const int2 o = make_int2(run, run + d.x);
        ((int2*)offs)[i2] = o;
        ((int2*)cursor)[i2] = o;
    }
}

// ---------------- counting-sort fill + per-edge head weights
__global__ __launch_bounds__(256) void fillsort_k(const int* __restrict__ ei,
                                                  const float* __restrict__ s_src,
                                                  const float* __restrict__ s_tgt,
                                                  int* __restrict__ cursor,
                                                  int* __restrict__ sorted_src,
                                                  float4* __restrict__ wts) {
    const int e = blockIdx.x * 256 + threadIdx.x;
    if (e >= EE) return;
    const int src = ei[e];
    const int tgt = ei[EE + e];
    const float4 a = *(const float4*)(s_src + (size_t)src * 4);
    const float4 b = *(const float4*)(s_tgt + (size_t)tgt * 4);
    float sc[4] = {a.x + b.x, a.y + b.y, a.z + b.z, a.w + b.w};
    float w[4];
#pragma unroll
    for (int i = 0; i < 4; ++i) {
        float lr = sc[i] > 0.f ? sc[i] : 0.2f * sc[i];
        w[i] = __expf(-lr);
    }
    const int pos = atomicAdd(cursor + tgt, 1);
    sorted_src[pos] = src;
    wts[pos] = make_float4(w[0], w[1], w[2], w[3]);
}

// ---------------- gather: one wave per node, finalize fused
__global__ __launch_bounds__(256) void gather_k(const int* __restrict__ offs,
                                                const int* __restrict__ sorted_src,
                                                const float* __restrict__ wts,
                                                const float* __restrict__ h,
                                                const float* __restrict__ bias,
                                                float* __restrict__ out) {
    const int n = blockIdx.x * 4 + (threadIdx.x >> 6);
    const int l = threadIdx.x & 63;
    const int c0 = l * 2;              // each lane: channels c0, c0+1 (same head)
    const int hd = l >> 4;
    const int p0 = offs[n], p1 = offs[n + 1];
    float ax = 0.f, ay = 0.f, wsum = 0.f;
    int p = p0;
    for (; p + 1 < p1; p += 2) {
        const int s0 = sorted_src[p];
        const int s1 = sorted_src[p + 1];
        const float w0 = wts[(size_t)p * 4 + hd];
        const float w1 = wts[(size_t)(p + 1) * 4 + hd];
        const float2 h0 = *(const float2*)(h + (size_t)s0 * HO + c0);
        const float2 h1 = *(const float2*)(h + (size_t)s1 * HO + c0);
        ax = fmaf(w0, h0.x, ax); ay = fmaf(w0, h0.y, ay);
        ax = fmaf(w1, h1.x, ax); ay = fmaf(w1, h1.y, ay);
        wsum += w0 + w1;
    }
    if (p < p1) {
        const int s0 = sorted_src[p];
        const float w0 = wts[(size_t)p * 4 + hd];
        const float2 h0 = *(const float2*)(h + (size_t)s0 * HO + c0);
        ax = fmaf(w0, h0.x, ax); ay = fmaf(w0, h0.y, ay);
        wsum += w0;
    }
    const float inv = 1.f / fmaxf(wsum, 1e-10f);
    float2 o;
    o.x = ax * inv + bias[c0];
    o.y = ay * inv + bias[c0 + 1];
    *(float2*)(out + (size_t)n * HO + c0) = o;
}

extern "C" void kernel_launch(void* const* d_in, const int* in_sizes, int n_in,
                              void* d_out, int out_size, void* d_ws, size_t ws_size,
                              hipStream_t stream) {
    const float* x    = (const float*)d_in[0];
    const int*   ei   = (const int*)d_in[1];
    const float* W    = (const float*)d_in[2];
    const float* att  = (const float*)d_in[3];
    const float* bias = (const float*)d_in[4];
    float* out = (float*)d_out;

    char* ws = (char*)d_ws;
    const size_t H_B   = (size_t)NN * HO * 4;        // 51.2 MB
    const size_t WT_B  = (size_t)EE * 16;            // 25.6 MB
    const size_t SS_B  = (size_t)EE * 4;             // 6.4 MB
    const size_t S_B   = (size_t)NN * HEADS * 4;     // 1.6 MB
    const size_t DEG_B = (size_t)NN * 4;             // 400 KB
    const size_t OFF_B = ((size_t)(NN + 1) * 4 + 15) & ~15ull;
    const size_t BS_B  = 256 * 4;

    size_t o = 0;
    float*  h          = (float*)(ws + o); o += H_B;
    float4* wts        = (float4*)(ws + o); o += WT_B;
    int*    sorted_src = (int*)(ws + o); o += SS_B;
    float*  ssrc       = (float*)(ws + o); o += S_B;
    float*  stgt       = (float*)(ws + o); o += S_B;
    int*    deg        = (int*)(ws + o); o += DEG_B;
    int*    offs       = (int*)(ws + o); o += OFF_B;
    int*    cursor     = (int*)(ws + o); o += DEG_B;
    int*    blockSums  = (int*)(ws + o); o += BS_B;
    int*    blockOffs  = (int*)(ws + o); o += BS_B;

    hipMemsetAsync(deg, 0, DEG_B, stream);

    gemm_h<<<NN / 32, 256, 0, stream>>>(x, W, h);                         // 3125 blocks
    s_kernel<<<(NN * HEADS) / 32, 256, 0, stream>>>(h, att, ssrc, stgt);  // 12500 blocks
    hist_k<<<(EE + 255) / 256, 256, 0, stream>>>(ei, deg);                // 6250 blocks
    blocksum_k<<<SCAN_BLOCKS, 256, 0, stream>>>(deg, blockSums);
    scansums_k<<<1, 256, 0, stream>>>(blockSums, blockOffs, offs);
    scanapply_k<<<SCAN_BLOCKS, 256, 0, stream>>>(deg, blockOffs, offs, cursor);
    fillsort_k<<<(EE + 255) / 256, 256, 0, stream>>>(ei, ssrc, stgt, cursor,
                                                     sorted_src, wts);    // 6250 blocks
    gather_k<<<NN / 4, 256, 0, stream>>>(offs, sorted_src, (const float*)wts,
                                         h, bias, out);                   // 25000 blocks
}

// Round 5
// 407.094 us; speedup vs baseline: 7.2014x; 1.0999x over previous
//
#include <hip/hip_runtime.h>
#include <stdint.h>

// GATConv: N=100000 nodes, E=1600000 edges, IN=128, HEADS=4, OUT=32 (HO=128)
// fp32 tensors; edge_index int32.
//
// R5: gemm fuses s_src/s_tgt epilogue + writes h as bf16 (halves gather bytes);
// fillsort writes only sorted_src (weights recomputed in gather from L2-resident
// s arrays); gather unrolled x4 for MLP. 3-pass parallel scan kept.

#define NN 100000
#define EE 1600000
#define INCH 128
#define HO 128           // HEADS*OUT
#define HEADS 4
#define OUTC 32

#define SCAN_BLOCKS 250  // 250 * 400 = 100000

typedef unsigned short ushort_t;
typedef unsigned int uint_t;

__device__ __forceinline__ float bfl(uint_t u) { return __uint_as_float(u << 16); }
__device__ __forceinline__ float bfh(uint_t u) { return __uint_as_float(u & 0xffff0000u); }
__device__ __forceinline__ uint_t f2bf(float f) {
    uint_t u = __float_as_uint(f);
    u = (u + 0x7fffu + ((u >> 16) & 1u)) >> 16;   // round-to-nearest-even
    return u;
}

// ---------------- GEMM + fused attention-score epilogue
// h_bf16[n][c] = bf16( sum_k x[n][k]*W[k][c] );  s_src/s_tgt[n][hd] from fp32 acc.
__global__ __launch_bounds__(256) void gemm_h(const float* __restrict__ x,
                                              const float* __restrict__ W,
                                              const float* __restrict__ att,
                                              ushort_t* __restrict__ hb,
                                              float* __restrict__ s_src,
                                              float* __restrict__ s_tgt) {
    __shared__ __align__(16) float wsm[128 * 128];   // 64 KB
    __shared__ __align__(16) float xs[32 * 128];     // 16 KB
    const int tid = threadIdx.x;
    const int row0 = blockIdx.x * 32;

    const float4* W4 = (const float4*)W;
    float4* w4 = (float4*)wsm;
#pragma unroll
    for (int i = 0; i < 16; ++i) w4[tid + 256 * i] = W4[tid + 256 * i];

    const float4* x4 = (const float4*)(x + (size_t)row0 * INCH);
    float4* xs4 = (float4*)xs;
#pragma unroll
    for (int i = 0; i < 4; ++i) xs4[tid + 256 * i] = x4[tid + 256 * i];

    const int rg = tid >> 5, cg = tid & 31;
    const int r0 = rg * 4, c0 = cg * 4;
    const int hd = cg >> 3;            // head of this thread's 4 columns
    const int co = c0 & 31;            // offset within head
    // attention fragments for this thread's 4 columns (global, L2-resident)
    const float4 as = *(const float4*)(att + hd * 64 + co);
    const float4 at = *(const float4*)(att + hd * 64 + 32 + co);
    __syncthreads();

    float acc[4][4] = {};
#pragma unroll 8
    for (int k = 0; k < 128; ++k) {
        const float4 wv = *(const float4*)(wsm + k * 128 + c0);
        float xv[4];
#pragma unroll
        for (int i = 0; i < 4; ++i) xv[i] = xs[(r0 + i) * 128 + k];
#pragma unroll
        for (int i = 0; i < 4; ++i) {
            acc[i][0] = fmaf(xv[i], wv.x, acc[i][0]);
            acc[i][1] = fmaf(xv[i], wv.y, acc[i][1]);
            acc[i][2] = fmaf(xv[i], wv.z, acc[i][2]);
            acc[i][3] = fmaf(xv[i], wv.w, acc[i][3]);
        }
    }
    // h write (bf16)
#pragma unroll
    for (int i = 0; i < 4; ++i) {
        uint2 st2;
        st2.x = f2bf(acc[i][0]) | (f2bf(acc[i][1]) << 16);
        st2.y = f2bf(acc[i][2]) | (f2bf(acc[i][3]) << 16);
        *(uint2*)(hb + (size_t)(row0 + r0 + i) * HO + c0) = st2;
    }
    // fused s epilogue: per-row partial dots, reduce across the 8 lanes of this head
    float ssp[4], stp[4];
#pragma unroll
    for (int i = 0; i < 4; ++i) {
        ssp[i] = acc[i][0] * as.x + acc[i][1] * as.y + acc[i][2] * as.z + acc[i][3] * as.w;
        stp[i] = acc[i][0] * at.x + acc[i][1] * at.y + acc[i][2] * at.z + acc[i][3] * at.w;
    }
#pragma unroll
    for (int d = 1; d < 8; d <<= 1) {
#pragma unroll
        for (int i = 0; i < 4; ++i) {
            ssp[i] += __shfl_xor(ssp[i], d, 64);
            stp[i] += __shfl_xor(stp[i], d, 64);
        }
    }
    if ((cg & 7) == 0) {
#pragma unroll
        for (int i = 0; i < 4; ++i) {
            const int row = row0 + r0 + i;
            s_src[row * 4 + hd] = ssp[i];
            s_tgt[row * 4 + hd] = stp[i];
        }
    }
}

// ---------------- histogram of tgt degrees
__global__ __launch_bounds__(256) void hist_k(const int* __restrict__ ei,
                                              int* __restrict__ deg) {
    const int e = blockIdx.x * 256 + threadIdx.x;
    if (e < EE) atomicAdd(deg + ei[EE + e], 1);
}

// ---------------- scan pass 1: per-block chunk sums
__global__ __launch_bounds__(256) void blocksum_k(const int* __restrict__ deg,
                                                  int* __restrict__ blockSums) {
    __shared__ int red[256];
    const int t = threadIdx.x;
    const int i2 = blockIdx.x * 200 + t;     // int2 index, 200 per block
    int s = 0;
    if (t < 200) {
        const int2 d = ((const int2*)deg)[i2];
        s = d.x + d.y;
    }
    red[t] = s;
    __syncthreads();
#pragma unroll
    for (int off = 128; off > 0; off >>= 1) {
        if (t < off) red[t] += red[t + off];
        __syncthreads();
    }
    if (t == 0) blockSums[blockIdx.x] = red[0];
}

// ---------------- scan pass 2: exclusive scan of 250 block sums
__global__ __launch_bounds__(256) void scansums_k(const int* __restrict__ blockSums,
                                                  int* __restrict__ blockOffs,
                                                  int* __restrict__ offs) {
    __shared__ int p[256];
    const int t = threadIdx.x;
    int v = (t < SCAN_BLOCKS) ? blockSums[t] : 0;
    p[t] = v;
    __syncthreads();
#pragma unroll
    for (int off = 1; off < 256; off <<= 1) {
        int u = (t >= off) ? p[t - off] : 0;
        __syncthreads();
        p[t] += u;
        __syncthreads();
    }
    if (t < SCAN_BLOCKS) blockOffs[t] = p[t] - v;   // exclusive
    if (t == 0) offs[NN] = EE;
}

// ---------------- scan pass 3: apply — write offs & cursor
__global__ __launch_bounds__(256) void scanapply_k(const int* __restrict__ deg,
                                                   const int* __restrict__ blockOffs,
                                                   int* __restrict__ offs,
                                                   int* __restrict__ cursor) {
    __shared__ int p[256];
    const int t = threadIdx.x;
    const int i2 = blockIdx.x * 200 + t;
    int2 d = make_int2(0, 0);
    if (t < 200) d = ((const int2*)deg)[i2];
    const int s = d.x + d.y;
    p[t] = s;
    __syncthreads();
#pragma unroll
    for (int off = 1; off < 256; off <<= 1) {
        int u = (t >= off) ? p[t - off] : 0;
        __syncthreads();
        p[t] += u;
        __syncthreads();
    }
    if (t < 200) {
        const int run = blockOffs[blockIdx.x] + p[t] - s;   // exclusive prefix
        const int2 o = make_int2(run, run + d.x);
        ((int2*)offs)[i2] = o;
        ((int2*)cursor)[i2] = o;
    }
}

// ---------------- counting-sort fill: src only
__global__ __launch_bounds__(256) void fillsort_k(const int* __restrict__ ei,
                                                  int* __restrict__ cursor,
                                                  int* __restrict__ sorted_src) {
    const int e = blockIdx.x * 256 + threadIdx.x;
    if (e >= EE) return;
    const int src = ei[e];
    const int tgt = ei[EE + e];
    const int pos = atomicAdd(cursor + tgt, 1);
    sorted_src[pos] = src;
}

// ---------------- gather: one wave per node, weights recomputed, finalize fused
__global__ __launch_bounds__(256) void gather_k(const int* __restrict__ offs,
                                                const int* __restrict__ sorted_src,
                                                const float* __restrict__ s_src,
                                                const float* __restrict__ s_tgt,
                                                const ushort_t* __restrict__ hb,
                                                const float* __restrict__ bias,
                                                float* __restrict__ out) {
    const int n = blockIdx.x * 4 + (threadIdx.x >> 6);
    const int l = threadIdx.x & 63;
    const int c0 = l * 2;              // two channels per lane (same head)
    const int hd = l >> 4;
    const int p0 = offs[n], p1 = offs[n + 1];
    const float st = s_tgt[n * 4 + hd];
    float ax = 0.f, ay = 0.f, wsum = 0.f;
    int p = p0;
    for (; p + 3 < p1; p += 4) {
        const int s0 = sorted_src[p];
        const int s1 = sorted_src[p + 1];
        const int s2 = sorted_src[p + 2];
        const int s3 = sorted_src[p + 3];
        const float sc0 = s_src[s0 * 4 + hd] + st;
        const float sc1 = s_src[s1 * 4 + hd] + st;
        const float sc2 = s_src[s2 * 4 + hd] + st;
        const float sc3 = s_src[s3 * 4 + hd] + st;
        const uint_t v0 = *(const uint_t*)(hb + (size_t)s0 * HO + c0);
        const uint_t v1 = *(const uint_t*)(hb + (size_t)s1 * HO + c0);
        const uint_t v2 = *(const uint_t*)(hb + (size_t)s2 * HO + c0);
        const uint_t v3 = *(const uint_t*)(hb + (size_t)s3 * HO + c0);
        const float w0 = __expf(-(sc0 > 0.f ? sc0 : 0.2f * sc0));
        const float w1 = __expf(-(sc1 > 0.f ? sc1 : 0.2f * sc1));
        const float w2 = __expf(-(sc2 > 0.f ? sc2 : 0.2f * sc2));
        const float w3 = __expf(-(sc3 > 0.f ? sc3 : 0.2f * sc3));
        ax = fmaf(w0, bfl(v0), ax); ay = fmaf(w0, bfh(v0), ay);
        ax = fmaf(w1, bfl(v1), ax); ay = fmaf(w1, bfh(v1), ay);
        ax = fmaf(w2, bfl(v2), ax); ay = fmaf(w2, bfh(v2), ay);
        ax = fmaf(w3, bfl(v3), ax); ay = fmaf(w3, bfh(v3), ay);
        wsum += (w0 + w1) + (w2 + w3);
    }
    for (; p < p1; ++p) {
        const int s0 = sorted_src[p];
        const float sc0 = s_src[s0 * 4 + hd] + st;
        const uint_t v0 = *(const uint_t*)(hb + (size_t)s0 * HO + c0);
        const float w0 = __expf(-(sc0 > 0.f ? sc0 : 0.2f * sc0));
        ax = fmaf(w0, bfl(v0), ax); ay = fmaf(w0, bfh(v0), ay);
        wsum += w0;
    }
    const float inv = 1.f / fmaxf(wsum, 1e-10f);
    float2 o;
    o.x = ax * inv + bias[c0];
    o.y = ay * inv + bias[c0 + 1];
    *(float2*)(out + (size_t)n * HO + c0) = o;
}

extern "C" void kernel_launch(void* const* d_in, const int* in_sizes, int n_in,
                              void* d_out, int out_size, void* d_ws, size_t ws_size,
                              hipStream_t stream) {
    const float* x    = (const float*)d_in[0];
    const int*   ei   = (const int*)d_in[1];
    const float* W    = (const float*)d_in[2];
    const float* att  = (const float*)d_in[3];
    const float* bias = (const float*)d_in[4];
    float* out = (float*)d_out;

    char* ws = (char*)d_ws;
    const size_t HB_B  = (size_t)NN * HO * 2;        // 25.6 MB (bf16 h)
    const size_t SS_B  = (size_t)EE * 4;             // 6.4 MB
    const size_t S_B   = (size_t)NN * HEADS * 4;     // 1.6 MB
    const size_t DEG_B = (size_t)NN * 4;             // 400 KB
    const size_t OFF_B = ((size_t)(NN + 1) * 4 + 15) & ~15ull;
    const size_t BS_B  = 256 * 4;

    size_t o = 0;
    ushort_t* hb         = (ushort_t*)(ws + o); o += HB_B;
    int*      sorted_src = (int*)(ws + o); o += SS_B;
    float*    ssrc       = (float*)(ws + o); o += S_B;
    float*    stgt       = (float*)(ws + o); o += S_B;
    int*      deg        = (int*)(ws + o); o += DEG_B;
    int*      offs       = (int*)(ws + o); o += OFF_B;
    int*      cursor     = (int*)(ws + o); o += DEG_B;
    int*      blockSums  = (int*)(ws + o); o += BS_B;
    int*      blockOffs  = (int*)(ws + o); o += BS_B;

    hipMemsetAsync(deg, 0, DEG_B, stream);

    gemm_h<<<NN / 32, 256, 0, stream>>>(x, W, att, hb, ssrc, stgt);       // 3125 blocks
    hist_k<<<(EE + 255) / 256, 256, 0, stream>>>(ei, deg);                // 6250 blocks
    blocksum_k<<<SCAN_BLOCKS, 256, 0, stream>>>(deg, blockSums);
    scansums_k<<<1, 256, 0, stream>>>(blockSums, blockOffs, offs);
    scanapply_k<<<SCAN_BLOCKS, 256, 0, stream>>>(deg, blockOffs, offs, cursor);
    fillsort_k<<<(EE + 255) / 256, 256, 0, stream>>>(ei, cursor, sorted_src); // 6250 blocks
    gather_k<<<NN / 4, 256, 0, stream>>>(offs, sorted_src, ssrc, stgt,
                                         hb, bias, out);                  // 25000 blocks
}

// Round 6
// 365.392 us; speedup vs baseline: 8.0233x; 1.1141x over previous
//
#include <hip/hip_runtime.h>
#include <stdint.h>

// GATConv: N=100000 nodes, E=1600000 edges, IN=128, HEADS=4, OUT=32 (HO=128)
// fp32 tensors; edge_index int32.
//
// R6: fillsort's random 4B scatter (16x line write amplification, 106MB HBM)
// replaced by 2-pass bucketed counting sort: bucketA (LDS-binned scatter into
// 391 CSR-aligned bucket regions, coalesced runs) + bucketB (per-bucket LDS
// counting sort, fully coalesced output).

#define NN 100000
#define EE 1600000
#define INCH 128
#define HO 128           // HEADS*OUT
#define HEADS 4
#define OUTC 32

#define SCAN_BLOCKS 250  // 250 * 400 = 100000

#define BSH 8                             // 256 nodes per bucket
#define NBUCK ((NN + 255) >> BSH)         // 391
#define CHA 8192                          // edges per bucketA block
#define ABLK ((EE + CHA - 1) / CHA)       // 196
#define CAPB 8192                         // bucketB LDS record capacity

typedef unsigned short ushort_t;
typedef unsigned int uint_t;

__device__ __forceinline__ float bfl(uint_t u) { return __uint_as_float(u << 16); }
__device__ __forceinline__ float bfh(uint_t u) { return __uint_as_float(u & 0xffff0000u); }
__device__ __forceinline__ uint_t f2bf(float f) {
    uint_t u = __float_as_uint(f);
    u = (u + 0x7fffu + ((u >> 16) & 1u)) >> 16;   // round-to-nearest-even
    return u;
}

// ---------------- GEMM + fused attention-score epilogue
__global__ __launch_bounds__(256) void gemm_h(const float* __restrict__ x,
                                              const float* __restrict__ W,
                                              const float* __restrict__ att,
                                              ushort_t* __restrict__ hb,
                                              float* __restrict__ s_src,
                                              float* __restrict__ s_tgt) {
    __shared__ __align__(16) float wsm[128 * 128];   // 64 KB
    __shared__ __align__(16) float xs[32 * 128];     // 16 KB
    const int tid = threadIdx.x;
    const int row0 = blockIdx.x * 32;

    const float4* W4 = (const float4*)W;
    float4* w4 = (float4*)wsm;
#pragma unroll
    for (int i = 0; i < 16; ++i) w4[tid + 256 * i] = W4[tid + 256 * i];

    const float4* x4 = (const float4*)(x + (size_t)row0 * INCH);
    float4* xs4 = (float4*)xs;
#pragma unroll
    for (int i = 0; i < 4; ++i) xs4[tid + 256 * i] = x4[tid + 256 * i];

    const int rg = tid >> 5, cg = tid & 31;
    const int r0 = rg * 4, c0 = cg * 4;
    const int hd = cg >> 3;            // head of this thread's 4 columns
    const int co = c0 & 31;            // offset within head
    const float4 as = *(const float4*)(att + hd * 64 + co);
    const float4 at = *(const float4*)(att + hd * 64 + 32 + co);
    __syncthreads();

    float acc[4][4] = {};
#pragma unroll 8
    for (int k = 0; k < 128; ++k) {
        const float4 wv = *(const float4*)(wsm + k * 128 + c0);
        float xv[4];
#pragma unroll
        for (int i = 0; i < 4; ++i) xv[i] = xs[(r0 + i) * 128 + k];
#pragma unroll
        for (int i = 0; i < 4; ++i) {
            acc[i][0] = fmaf(xv[i], wv.x, acc[i][0]);
            acc[i][1] = fmaf(xv[i], wv.y, acc[i][1]);
            acc[i][2] = fmaf(xv[i], wv.z, acc[i][2]);
            acc[i][3] = fmaf(xv[i], wv.w, acc[i][3]);
        }
    }
#pragma unroll
    for (int i = 0; i < 4; ++i) {
        uint2 st2;
        st2.x = f2bf(acc[i][0]) | (f2bf(acc[i][1]) << 16);
        st2.y = f2bf(acc[i][2]) | (f2bf(acc[i][3]) << 16);
        *(uint2*)(hb + (size_t)(row0 + r0 + i) * HO + c0) = st2;
    }
    float ssp[4], stp[4];
#pragma unroll
    for (int i = 0; i < 4; ++i) {
        ssp[i] = acc[i][0] * as.x + acc[i][1] * as.y + acc[i][2] * as.z + acc[i][3] * as.w;
        stp[i] = acc[i][0] * at.x + acc[i][1] * at.y + acc[i][2] * at.z + acc[i][3] * at.w;
    }
#pragma unroll
    for (int d = 1; d < 8; d <<= 1) {
#pragma unroll
        for (int i = 0; i < 4; ++i) {
            ssp[i] += __shfl_xor(ssp[i], d, 64);
            stp[i] += __shfl_xor(stp[i], d, 64);
        }
    }
    if ((cg & 7) == 0) {
#pragma unroll
        for (int i = 0; i < 4; ++i) {
            const int row = row0 + r0 + i;
            s_src[row * 4 + hd] = ssp[i];
            s_tgt[row * 4 + hd] = stp[i];
        }
    }
}

// ---------------- histogram of tgt degrees
__global__ __launch_bounds__(256) void hist_k(const int* __restrict__ ei,
                                              int* __restrict__ deg) {
    const int e = blockIdx.x * 256 + threadIdx.x;
    if (e < EE) atomicAdd(deg + ei[EE + e], 1);
}

// ---------------- scan pass 1: per-block chunk sums
__global__ __launch_bounds__(256) void blocksum_k(const int* __restrict__ deg,
                                                  int* __restrict__ blockSums) {
    __shared__ int red[256];
    const int t = threadIdx.x;
    const int i2 = blockIdx.x * 200 + t;     // int2 index, 200 per block
    int s = 0;
    if (t < 200) {
        const int2 d = ((const int2*)deg)[i2];
        s = d.x + d.y;
    }
    red[t] = s;
    __syncthreads();
#pragma unroll
    for (int off = 128; off > 0; off >>= 1) {
        if (t < off) red[t] += red[t + off];
        __syncthreads();
    }
    if (t == 0) blockSums[blockIdx.x] = red[0];
}

// ---------------- scan pass 2: exclusive scan of 250 block sums
__global__ __launch_bounds__(256) void scansums_k(const int* __restrict__ blockSums,
                                                  int* __restrict__ blockOffs,
                                                  int* __restrict__ offs) {
    __shared__ int p[256];
    const int t = threadIdx.x;
    int v = (t < SCAN_BLOCKS) ? blockSums[t] : 0;
    p[t] = v;
    __syncthreads();
#pragma unroll
    for (int off = 1; off < 256; off <<= 1) {
        int u = (t >= off) ? p[t - off] : 0;
        __syncthreads();
        p[t] += u;
        __syncthreads();
    }
    if (t < SCAN_BLOCKS) blockOffs[t] = p[t] - v;   // exclusive
    if (t == 0) offs[NN] = EE;
}

// ---------------- scan pass 3: apply — write offs & per-bucket cursors
__global__ __launch_bounds__(256) void scanapply_k(const int* __restrict__ deg,
                                                   const int* __restrict__ blockOffs,
                                                   int* __restrict__ offs,
                                                   int* __restrict__ gcur) {
    __shared__ int p[256];
    const int t = threadIdx.x;
    const int i2 = blockIdx.x * 200 + t;
    int2 d = make_int2(0, 0);
    if (t < 200) d = ((const int2*)deg)[i2];
    const int s = d.x + d.y;
    p[t] = s;
    __syncthreads();
#pragma unroll
    for (int off = 1; off < 256; off <<= 1) {
        int u = (t >= off) ? p[t - off] : 0;
        __syncthreads();
        p[t] += u;
        __syncthreads();
    }
    if (t < 200) {
        const int run = blockOffs[blockIdx.x] + p[t] - s;   // exclusive prefix
        const int2 o = make_int2(run, run + d.x);
        ((int2*)offs)[i2] = o;
        const int node = i2 * 2;
        if ((node & 255) == 0) gcur[node >> BSH] = run;     // bucket cursor seed
    }
}

// ---------------- bucket pass A: LDS-binned scatter into bucket regions
__global__ __launch_bounds__(256) void bucketA_k(const int* __restrict__ ei,
                                                 int* __restrict__ gcur,
                                                 uint_t* __restrict__ grec) {
    __shared__ int hist[NBUCK];
    __shared__ int lofs[NBUCK + 1];
    __shared__ int lcur[NBUCK];
    __shared__ int gbase[NBUCK];
    __shared__ int sc[256];
    __shared__ uint_t stag[CHA];        // 32 KB
    const int tid = threadIdx.x;
    const int e0 = blockIdx.x * CHA;
    const int cnt = min(CHA, EE - e0);

    for (int b = tid; b < NBUCK; b += 256) hist[b] = 0;
    __syncthreads();
    for (int i = tid; i < cnt; i += 256)
        atomicAdd(&hist[ei[EE + e0 + i] >> BSH], 1);
    __syncthreads();
    // exclusive scan of hist -> lofs (2 entries per thread, NBUCK=391<=512)
    const int b0 = 2 * tid, b1 = 2 * tid + 1;
    const int h0 = (b0 < NBUCK) ? hist[b0] : 0;
    const int h1 = (b1 < NBUCK) ? hist[b1] : 0;
    sc[tid] = h0 + h1;
    __syncthreads();
#pragma unroll
    for (int off = 1; off < 256; off <<= 1) {
        int u = (tid >= off) ? sc[tid - off] : 0;
        __syncthreads();
        sc[tid] += u;
        __syncthreads();
    }
    const int ex = sc[tid] - (h0 + h1);
    if (b0 < NBUCK) { lofs[b0] = ex;      lcur[b0] = ex; }
    if (b1 < NBUCK) { lofs[b1] = ex + h0; lcur[b1] = ex + h0; }
    if (tid == 0) lofs[NBUCK] = cnt;
    __syncthreads();
    // reserve global runs (one atomic per bucket per block)
    for (int b = tid; b < NBUCK; b += 256) gbase[b] = atomicAdd(&gcur[b], hist[b]);
    // bin packed records into LDS staging
    for (int i = tid; i < cnt; i += 256) {
        const int src = ei[e0 + i];
        const int tgt = ei[EE + e0 + i];
        const int b = tgt >> BSH;
        const int p = atomicAdd(&lcur[b], 1);
        stag[p] = (uint_t)src | ((uint_t)(tgt & 255) << 17);   // src<2^17
    }
    __syncthreads();
    // coalesced run writes (binary search for bucket of staging index)
    for (int i = tid; i < cnt; i += 256) {
        int lo = 0, hi = NBUCK - 1;
        while (lo < hi) {
            const int mid = (lo + hi + 1) >> 1;
            if (lofs[mid] <= i) lo = mid; else hi = mid - 1;
        }
        grec[gbase[lo] + (i - lofs[lo])] = stag[i];
    }
}

// ---------------- bucket pass B: per-bucket LDS counting sort -> sorted_src
__global__ __launch_bounds__(256) void bucketB_k(const int* __restrict__ offs,
                                                 const uint_t* __restrict__ grec,
                                                 int* __restrict__ sorted_src) {
    __shared__ int cur[256];
    __shared__ int sbuf[CAPB];          // 32 KB
    const int tid = threadIdx.x;
    const int b = blockIdx.x;
    const int n0 = b << BSH;
    const int nn = min(256, NN - n0);
    const int R0 = offs[n0];
    const int R1 = offs[min(n0 + 256, NN)];
    const int cnt = R1 - R0;
    if (tid < nn) cur[tid] = offs[n0 + tid] - R0;
    __syncthreads();
    if (cnt <= CAPB) {
        for (int i = tid; i < cnt; i += 256) {
            const uint_t r = grec[R0 + i];
            const int p = atomicAdd(&cur[r >> 17], 1);
            sbuf[p] = (int)(r & 0x1FFFF);
        }
        __syncthreads();
        for (int i = tid; i < cnt; i += 256) sorted_src[R0 + i] = sbuf[i];
    } else {   // statistically unreachable fallback (>= 64 sigma)
        for (int i = tid; i < cnt; i += 256) {
            const uint_t r = grec[R0 + i];
            const int p = atomicAdd(&cur[r >> 17], 1);
            sorted_src[R0 + p] = (int)(r & 0x1FFFF);
        }
    }
}

// ---------------- gather: one wave per node, weights recomputed, finalize fused
__global__ __launch_bounds__(256) void gather_k(const int* __restrict__ offs,
                                                const int* __restrict__ sorted_src,
                                                const float* __restrict__ s_src,
                                                const float* __restrict__ s_tgt,
                                                const ushort_t* __restrict__ hb,
                                                const float* __restrict__ bias,
                                                float* __restrict__ out) {
    const int n = blockIdx.x * 4 + (threadIdx.x >> 6);
    const int l = threadIdx.x & 63;
    const int c0 = l * 2;              // two channels per lane (same head)
    const int hd = l >> 4;
    const int p0 = offs[n], p1 = offs[n + 1];
    const float st = s_tgt[n * 4 + hd];
    float ax = 0.f, ay = 0.f, wsum = 0.f;
    int p = p0;
    for (; p + 3 < p1; p += 4) {
        const int s0 = sorted_src[p];
        const int s1 = sorted_src[p + 1];
        const int s2 = sorted_src[p + 2];
        const int s3 = sorted_src[p + 3];
        const float sc0 = s_src[s0 * 4 + hd] + st;
        const float sc1 = s_src[s1 * 4 + hd] + st;
        const float sc2 = s_src[s2 * 4 + hd] + st;
        const float sc3 = s_src[s3 * 4 + hd] + st;
        const uint_t v0 = *(const uint_t*)(hb + (size_t)s0 * HO + c0);
        const uint_t v1 = *(const uint_t*)(hb + (size_t)s1 * HO + c0);
        const uint_t v2 = *(const uint_t*)(hb + (size_t)s2 * HO + c0);
        const uint_t v3 = *(const uint_t*)(hb + (size_t)s3 * HO + c0);
        const float w0 = __expf(-(sc0 > 0.f ? sc0 : 0.2f * sc0));
        const float w1 = __expf(-(sc1 > 0.f ? sc1 : 0.2f * sc1));
        const float w2 = __expf(-(sc2 > 0.f ? sc2 : 0.2f * sc2));
        const float w3 = __expf(-(sc3 > 0.f ? sc3 : 0.2f * sc3));
        ax = fmaf(w0, bfl(v0), ax); ay = fmaf(w0, bfh(v0), ay);
        ax = fmaf(w1, bfl(v1), ax); ay = fmaf(w1, bfh(v1), ay);
        ax = fmaf(w2, bfl(v2), ax); ay = fmaf(w2, bfh(v2), ay);
        ax = fmaf(w3, bfl(v3), ax); ay = fmaf(w3, bfh(v3), ay);
        wsum += (w0 + w1) + (w2 + w3);
    }
    for (; p < p1; ++p) {
        const int s0 = sorted_src[p];
        const float sc0 = s_src[s0 * 4 + hd] + st;
        const uint_t v0 = *(const uint_t*)(hb + (size_t)s0 * HO + c0);
        const float w0 = __expf(-(sc0 > 0.f ? sc0 : 0.2f * sc0));
        ax = fmaf(w0, bfl(v0), ax); ay = fmaf(w0, bfh(v0), ay);
        wsum += w0;
    }
    const float inv = 1.f / fmaxf(wsum, 1e-10f);
    float2 o;
    o.x = ax * inv + bias[c0];
    o.y = ay * inv + bias[c0 + 1];
    *(float2*)(out + (size_t)n * HO + c0) = o;
}

extern "C" void kernel_launch(void* const* d_in, const int* in_sizes, int n_in,
                              void* d_out, int out_size, void* d_ws, size_t ws_size,
                              hipStream_t stream) {
    const float* x    = (const float*)d_in[0];
    const int*   ei   = (const int*)d_in[1];
    const float* W    = (const float*)d_in[2];
    const float* att  = (const float*)d_in[3];
    const float* bias = (const float*)d_in[4];
    float* out = (float*)d_out;

    char* ws = (char*)d_ws;
    const size_t HB_B  = (size_t)NN * HO * 2;        // 25.6 MB (bf16 h)
    const size_t SS_B  = (size_t)EE * 4;             // 6.4 MB
    const size_t GR_B  = (size_t)EE * 4;             // 6.4 MB (packed records)
    const size_t S_B   = (size_t)NN * HEADS * 4;     // 1.6 MB
    const size_t DEG_B = (size_t)NN * 4;             // 400 KB
    const size_t OFF_B = ((size_t)(NN + 1) * 4 + 15) & ~15ull;
    const size_t BS_B  = 256 * 4;
    const size_t GC_B  = ((size_t)NBUCK * 4 + 15) & ~15ull;

    size_t o = 0;
    ushort_t* hb         = (ushort_t*)(ws + o); o += HB_B;
    int*      sorted_src = (int*)(ws + o); o += SS_B;
    uint_t*   grec       = (uint_t*)(ws + o); o += GR_B;
    float*    ssrc       = (float*)(ws + o); o += S_B;
    float*    stgt       = (float*)(ws + o); o += S_B;
    int*      deg        = (int*)(ws + o); o += DEG_B;
    int*      offs       = (int*)(ws + o); o += OFF_B;
    int*      gcur       = (int*)(ws + o); o += GC_B;
    int*      blockSums  = (int*)(ws + o); o += BS_B;
    int*      blockOffs  = (int*)(ws + o); o += BS_B;

    hipMemsetAsync(deg, 0, DEG_B, stream);

    gemm_h<<<NN / 32, 256, 0, stream>>>(x, W, att, hb, ssrc, stgt);       // 3125 blocks
    hist_k<<<(EE + 255) / 256, 256, 0, stream>>>(ei, deg);                // 6250 blocks
    blocksum_k<<<SCAN_BLOCKS, 256, 0, stream>>>(deg, blockSums);
    scansums_k<<<1, 256, 0, stream>>>(blockSums, blockOffs, offs);
    scanapply_k<<<SCAN_BLOCKS, 256, 0, stream>>>(deg, blockOffs, offs, gcur);
    bucketA_k<<<ABLK, 256, 0, stream>>>(ei, gcur, grec);                  // 196 blocks
    bucketB_k<<<NBUCK, 256, 0, stream>>>(offs, grec, sorted_src);         // 391 blocks
    gather_k<<<NN / 4, 256, 0, stream>>>(offs, sorted_src, ssrc, stgt,
                                         hb, bias, out);                  // 25000 blocks
}